// Round 1
// baseline (1599.549 us; speedup 1.0000x reference)
//
#include <hip/hip_runtime.h>
#include <math.h>

// Problem constants (match reference; N/E re-derived from in_sizes at launch)
#define DIM      128   // D == H == 128
#define HEADS    8
#define HEAD_DIM 16
#define NCLS     64
#define NEG_SLOPE 0.2f

// ---------------------------------------------------------------- degree
__global__ void deg_kernel(const int* __restrict__ dst, float* __restrict__ deg, int E) {
    int e = blockIdx.x * blockDim.x + threadIdx.x;
    if (e < E) atomicAdd(&deg[dst[e]], 1.0f);
}

// ------------------------------------------------- edge scatter-add (128 feats)
__global__ void scatter_add_kernel(const float* __restrict__ x, const int* __restrict__ src,
                                   const int* __restrict__ dst, float* __restrict__ agg, int E) {
    long long tid = (long long)blockIdx.x * blockDim.x + threadIdx.x;
    long long total = (long long)E * DIM;
    if (tid >= total) return;
    int e = (int)(tid >> 7);
    int f = (int)(tid & 127);
    int s = src[e], d = dst[e];
    atomicAdd(&agg[(long long)d * DIM + f], x[(long long)s * DIM + f]);
}

// ------------------------------------- (agg/deg) @ W + b, relu  (block = node)
__global__ void gcn_linear_relu(const float* __restrict__ agg, const float* __restrict__ deg,
                                const float* __restrict__ W, const float* __restrict__ b,
                                float* __restrict__ out) {
    int n = blockIdx.x;
    int j = threadIdx.x;           // 128 threads
    __shared__ float row[DIM];
    float inv = 1.0f / fmaxf(deg[n], 1.0f);
    row[j] = agg[(long long)n * DIM + j] * inv;
    __syncthreads();
    float acc = b[j];
#pragma unroll 8
    for (int k = 0; k < DIM; ++k) acc = fmaf(row[k], W[k * DIM + j], acc);
    out[(long long)n * DIM + j] = fmaxf(acc, 0.0f);
}

// --------------------------- GAT: h = x @ Wg (no bias), plus e_s/e_d epilogue
__global__ void gat_h_kernel(const float* __restrict__ x, const float* __restrict__ Wg,
                             const float* __restrict__ a_src, const float* __restrict__ a_dst,
                             float* __restrict__ h, float* __restrict__ e_s, float* __restrict__ e_d) {
    int n = blockIdx.x;
    int j = threadIdx.x;           // 128 threads
    __shared__ float row[DIM];
    __shared__ float hrow[DIM];
    row[j] = x[(long long)n * DIM + j];
    __syncthreads();
    float acc = 0.0f;
#pragma unroll 8
    for (int k = 0; k < DIM; ++k) acc = fmaf(row[k], Wg[k * DIM + j], acc);
    h[(long long)n * DIM + j] = acc;
    hrow[j] = acc;
    __syncthreads();
    if (j < 2 * HEADS) {
        int head = j & (HEADS - 1);
        const float* av = (j < HEADS) ? a_src : a_dst;
        float s = 0.0f;
#pragma unroll
        for (int d = 0; d < HEAD_DIM; ++d)
            s = fmaf(hrow[head * HEAD_DIM + d], av[head * HEAD_DIM + d], s);
        ((j < HEADS) ? e_s : e_d)[n * HEADS + head] = s;
    }
}

// ------------------- per edge-head: exp(leaky_relu(e_s[src]+e_d[dst])), denom
__global__ void gat_score_kernel(const int* __restrict__ src, const int* __restrict__ dst,
                                 const float* __restrict__ e_s, const float* __restrict__ e_d,
                                 float* __restrict__ sexp, float* __restrict__ denom, int E) {
    int tid = blockIdx.x * blockDim.x + threadIdx.x;
    if (tid >= E * HEADS) return;
    int e = tid >> 3;
    int hh = tid & (HEADS - 1);
    float sc = e_s[src[e] * HEADS + hh] + e_d[dst[e] * HEADS + hh];
    sc = (sc > 0.0f) ? sc : NEG_SLOPE * sc;
    float ex = expf(sc);            // max-subtraction skipped: |sc| <~ 8, safe in fp32
    sexp[tid] = ex;
    atomicAdd(&denom[dst[e] * HEADS + hh], ex);
}

// ----------------------------- weighted scatter: agg[dst] += h[src] * alpha
__global__ void gat_scatter_kernel(const float* __restrict__ h, const int* __restrict__ src,
                                   const int* __restrict__ dst, const float* __restrict__ sexp,
                                   const float* __restrict__ denom, float* __restrict__ agg, int E) {
    long long tid = (long long)blockIdx.x * blockDim.x + threadIdx.x;
    long long total = (long long)E * DIM;
    if (tid >= total) return;
    int e = (int)(tid >> 7);
    int f = (int)(tid & 127);
    int head = f >> 4;
    int d = dst[e];
    float alpha = sexp[e * HEADS + head] / (denom[d * HEADS + head] + 1e-9f);
    atomicAdd(&agg[(long long)d * DIM + f], h[(long long)src[e] * DIM + f] * alpha);
}

// --------- x_gat = relu(agg + bg); link = sigmoid(x_gat . Wl + bl)
__global__ void gat_out_kernel(const float* __restrict__ agg, const float* __restrict__ bg,
                               const float* __restrict__ Wl, const float* __restrict__ bl,
                               float* __restrict__ out_link) {
    int n = blockIdx.x;
    int j = threadIdx.x;           // 128 threads = 2 waves
    float xv = fmaxf(agg[(long long)n * DIM + j] + bg[j], 0.0f);
    float p = xv * Wl[j];
    for (int off = 32; off; off >>= 1) p += __shfl_xor(p, off);
    __shared__ float partial[2];
    if ((j & 63) == 0) partial[j >> 6] = p;
    __syncthreads();
    if (j == 0) {
        float s = partial[0] + partial[1] + bl[0];
        out_link[n] = 1.0f / (1.0f + expf(-s));
    }
}

// --------- classifier: softmax(x2 @ Wcls + bcls)   (block = node, 64 thr = 1 wave)
__global__ void classifier_kernel(const float* __restrict__ x2, const float* __restrict__ Wcls,
                                  const float* __restrict__ bcls, float* __restrict__ out) {
    int n = blockIdx.x;
    int j = threadIdx.x;           // 64 threads
    __shared__ float row[DIM];
    row[j]      = x2[(long long)n * DIM + j];
    row[j + 64] = x2[(long long)n * DIM + j + 64];
    __syncthreads();
    float acc = bcls[j];
#pragma unroll 8
    for (int k = 0; k < DIM; ++k) acc = fmaf(row[k], Wcls[k * NCLS + j], acc);
    float m = acc;
    for (int off = 32; off; off >>= 1) m = fmaxf(m, __shfl_xor(m, off));
    float e = expf(acc - m);
    float s = e;
    for (int off = 32; off; off >>= 1) s += __shfl_xor(s, off);
    out[(long long)n * NCLS + j] = e / s;
}

extern "C" void kernel_launch(void* const* d_in, const int* in_sizes, int n_in,
                              void* d_out, int out_size, void* d_ws, size_t ws_size,
                              hipStream_t stream) {
    const float* xin   = (const float*)d_in[0];
    const int*   eidx  = (const int*)  d_in[1];
    const float* W1    = (const float*)d_in[2];
    const float* b1    = (const float*)d_in[3];
    const float* W2    = (const float*)d_in[4];
    const float* b2    = (const float*)d_in[5];
    const float* Wg    = (const float*)d_in[6];
    const float* bg    = (const float*)d_in[7];
    const float* a_src = (const float*)d_in[8];
    const float* a_dst = (const float*)d_in[9];
    const float* Wcls  = (const float*)d_in[10];
    const float* bcls  = (const float*)d_in[11];
    const float* Wl    = (const float*)d_in[12];
    const float* bl    = (const float*)d_in[13];

    const int N = in_sizes[0] / DIM;
    const int E = in_sizes[1] / 2;
    const int* src = eidx;
    const int* dst = eidx + E;

    // workspace layout (floats): deg | bufA | bufB | e_s | e_d | denom | sexp
    float* ws    = (float*)d_ws;
    float* deg   = ws;
    float* bufA  = deg  + N;                       // N*DIM accumulator (agg1, agg2, gat_agg)
    float* bufB  = bufA + (size_t)N * DIM;         // N*DIM (x1, x2, then h)
    float* e_s   = bufB + (size_t)N * DIM;
    float* e_d   = e_s  + (size_t)N * HEADS;
    float* denom = e_d  + (size_t)N * HEADS;
    float* sexp  = denom + (size_t)N * HEADS;      // E*HEADS

    float* out_cls  = (float*)d_out;               // [N, 64]
    float* out_link = out_cls + (size_t)N * NCLS;  // [N, 1]

    long long totEF = (long long)E * DIM;
    int blkEF = (int)((totEF + 255) / 256);
    int blkE  = (E + 255) / 256;
    int blkEH = (E * HEADS + 255) / 256;

    // ---- GCN layer 1
    hipMemsetAsync(deg, 0, (size_t)N * sizeof(float), stream);
    hipMemsetAsync(bufA, 0, (size_t)N * DIM * sizeof(float), stream);
    deg_kernel<<<blkE, 256, 0, stream>>>(dst, deg, E);
    scatter_add_kernel<<<blkEF, 256, 0, stream>>>(xin, src, dst, bufA, E);
    gcn_linear_relu<<<N, DIM, 0, stream>>>(bufA, deg, W1, b1, bufB);      // bufB = x1

    // ---- GCN layer 2
    hipMemsetAsync(bufA, 0, (size_t)N * DIM * sizeof(float), stream);
    scatter_add_kernel<<<blkEF, 256, 0, stream>>>(bufB, src, dst, bufA, E);
    gcn_linear_relu<<<N, DIM, 0, stream>>>(bufA, deg, W2, b2, bufB);      // bufB = x2

    // ---- classifier head
    classifier_kernel<<<N, NCLS, 0, stream>>>(bufB, Wcls, bcls, out_cls);

    // ---- GAT (from original features); bufB reused for h after classifier
    gat_h_kernel<<<N, DIM, 0, stream>>>(xin, Wg, a_src, a_dst, bufB, e_s, e_d);
    hipMemsetAsync(denom, 0, (size_t)N * HEADS * sizeof(float), stream);
    hipMemsetAsync(bufA, 0, (size_t)N * DIM * sizeof(float), stream);
    gat_score_kernel<<<blkEH, 256, 0, stream>>>(src, dst, e_s, e_d, sexp, denom, E);
    gat_scatter_kernel<<<blkEF, 256, 0, stream>>>(bufB, src, dst, sexp, denom, bufA, E);
    gat_out_kernel<<<N, DIM, 0, stream>>>(bufA, bg, Wl, bl, out_link);
}

// Round 2
// 840.456 us; speedup vs baseline: 1.9032x; 1.9032x over previous
//
#include <hip/hip_runtime.h>
#include <math.h>

#define DIM      128
#define HEADS    8
#define HEAD_DIM 16
#define NCLS     64
#define NEG_SLOPE 0.2f
#define SCAN_THREADS 1024

// ----------------------------------------------------------- degree histogram
__global__ void deg_hist(const int* __restrict__ dst, int* __restrict__ deg, int E) {
    int e = blockIdx.x * blockDim.x + threadIdx.x;
    if (e < E) atomicAdd(&deg[dst[e]], 1);
}

// ------------------- single-block exclusive scan over N degrees -> rowstart
__global__ void scan_kernel(const int* __restrict__ deg, int* __restrict__ rowstart, int N) {
    __shared__ int sums[SCAN_THREADS];
    int t = threadIdx.x;
    int chunk = (N + SCAN_THREADS - 1) / SCAN_THREADS;
    int beg = t * chunk;
    int end = min(beg + chunk, N);
    int s = 0;
    for (int i = beg; i < end; ++i) s += deg[i];
    sums[t] = s;
    __syncthreads();
    for (int off = 1; off < SCAN_THREADS; off <<= 1) {
        int v = (t >= off) ? sums[t - off] : 0;
        __syncthreads();
        sums[t] += v;
        __syncthreads();
    }
    int run = (t == 0) ? 0 : sums[t - 1];
    for (int i = beg; i < end; ++i) { rowstart[i] = run; run += deg[i]; }
    if (t == SCAN_THREADS - 1) rowstart[N] = sums[SCAN_THREADS - 1];
}

// -------------------------------------------- bucket fill: 1 atomic per edge
__global__ void fill_csr(const int* __restrict__ src, const int* __restrict__ dst,
                         const int* __restrict__ rowstart, int* __restrict__ cursor,
                         int* __restrict__ csr_src, int* __restrict__ csr_eid, int E) {
    int e = blockIdx.x * blockDim.x + threadIdx.x;
    if (e >= E) return;
    int d = dst[e];
    int pos = rowstart[d] + atomicAdd(&cursor[d], 1);
    csr_src[pos] = src[e];
    csr_eid[pos] = e;
}

// ------- GCN layer: gather-sum over CSR bucket, deg-normalize, matvec, relu
__global__ void gcn_fused(const float* __restrict__ x, const int* __restrict__ rowstart,
                          const int* __restrict__ csr_src,
                          const float* __restrict__ W, const float* __restrict__ b,
                          float* __restrict__ out) {
    int n = blockIdx.x;
    int f = threadIdx.x;                    // 128 threads, one feature each
    int beg = rowstart[n], end = rowstart[n + 1];
    float s = 0.0f;
    for (int i = beg; i < end; ++i) {
        int sn = csr_src[i];
        s += x[(size_t)sn * DIM + f];       // 512B coalesced row per edge
    }
    float inv = 1.0f / fmaxf((float)(end - beg), 1.0f);
    __shared__ float row[DIM];
    row[f] = s * inv;
    __syncthreads();
    float acc = b[f];
#pragma unroll 8
    for (int k = 0; k < DIM; ++k) acc = fmaf(row[k], W[k * DIM + f], acc);
    out[(size_t)n * DIM + f] = fmaxf(acc, 0.0f);
}

// --------------------------- GAT: h = x @ Wg, plus e_s/e_d dot-product epilogue
__global__ void gat_h_kernel(const float* __restrict__ x, const float* __restrict__ Wg,
                             const float* __restrict__ a_src, const float* __restrict__ a_dst,
                             float* __restrict__ h, float* __restrict__ e_s, float* __restrict__ e_d) {
    int n = blockIdx.x;
    int j = threadIdx.x;                    // 128 threads
    __shared__ float row[DIM];
    __shared__ float hrow[DIM];
    row[j] = x[(size_t)n * DIM + j];
    __syncthreads();
    float acc = 0.0f;
#pragma unroll 8
    for (int k = 0; k < DIM; ++k) acc = fmaf(row[k], Wg[k * DIM + j], acc);
    h[(size_t)n * DIM + j] = acc;
    hrow[j] = acc;
    __syncthreads();
    if (j < 2 * HEADS) {
        int head = j & (HEADS - 1);
        const float* av = (j < HEADS) ? a_src : a_dst;
        float s = 0.0f;
#pragma unroll
        for (int d = 0; d < HEAD_DIM; ++d)
            s = fmaf(hrow[head * HEAD_DIM + d], av[head * HEAD_DIM + d], s);
        ((j < HEADS) ? e_s : e_d)[n * HEADS + head] = s;
    }
}

// ---------------- per edge-head: sexp = exp(leaky_relu(e_s[src]+e_d[dst]))
__global__ void gat_score(const int* __restrict__ src, const int* __restrict__ dst,
                          const float* __restrict__ e_s, const float* __restrict__ e_d,
                          float* __restrict__ sexp, int E) {
    int tid = blockIdx.x * blockDim.x + threadIdx.x;
    if (tid >= E * HEADS) return;
    int e = tid >> 3;
    int hh = tid & (HEADS - 1);
    float sc = e_s[src[e] * HEADS + hh] + e_d[dst[e] * HEADS + hh];
    sc = (sc > 0.0f) ? sc : NEG_SLOPE * sc;
    sexp[tid] = expf(sc);                   // max-shift skipped: |sc| small, fp32-safe
}

// ---- GAT aggregate: acc=Σ h[src]*exp, den=Σ exp (den const per node,head →
//      single loop, divide once), then bg/relu/Wl/sigmoid epilogue inline.
__global__ void gat_fused(const float* __restrict__ h, const int* __restrict__ rowstart,
                          const int* __restrict__ csr_src, const int* __restrict__ csr_eid,
                          const float* __restrict__ sexp, const float* __restrict__ bg,
                          const float* __restrict__ Wl, const float* __restrict__ bl,
                          float* __restrict__ out_link) {
    int n = blockIdx.x;
    int f = threadIdx.x;                    // 128 threads
    int head = f >> 4;
    int beg = rowstart[n], end = rowstart[n + 1];
    float acc = 0.0f, den = 0.0f;
    for (int i = beg; i < end; ++i) {
        int sn = csr_src[i];
        int eid = csr_eid[i];
        float ex = sexp[eid * HEADS + head];
        den += ex;
        acc = fmaf(h[(size_t)sn * DIM + f], ex, acc);
    }
    float xv = fmaxf(acc / (den + 1e-9f) + bg[f], 0.0f);
    float p = xv * Wl[f];
    for (int off = 32; off; off >>= 1) p += __shfl_xor(p, off);
    __shared__ float part[2];
    if ((f & 63) == 0) part[f >> 6] = p;
    __syncthreads();
    if (f == 0) out_link[n] = 1.0f / (1.0f + expf(-(part[0] + part[1] + bl[0])));
}

// --------- classifier: softmax(x2 @ Wcls + bcls)  (block = node, 1 wave)
__global__ void classifier_kernel(const float* __restrict__ x2, const float* __restrict__ Wcls,
                                  const float* __restrict__ bcls, float* __restrict__ out) {
    int n = blockIdx.x;
    int j = threadIdx.x;                    // 64 threads
    __shared__ float row[DIM];
    row[j]      = x2[(size_t)n * DIM + j];
    row[j + 64] = x2[(size_t)n * DIM + j + 64];
    __syncthreads();
    float acc = bcls[j];
#pragma unroll 8
    for (int k = 0; k < DIM; ++k) acc = fmaf(row[k], Wcls[k * NCLS + j], acc);
    float m = acc;
    for (int off = 32; off; off >>= 1) m = fmaxf(m, __shfl_xor(m, off));
    float e = expf(acc - m);
    float s = e;
    for (int off = 32; off; off >>= 1) s += __shfl_xor(s, off);
    out[(size_t)n * NCLS + j] = e / s;
}

extern "C" void kernel_launch(void* const* d_in, const int* in_sizes, int n_in,
                              void* d_out, int out_size, void* d_ws, size_t ws_size,
                              hipStream_t stream) {
    const float* xin   = (const float*)d_in[0];
    const int*   eidx  = (const int*)  d_in[1];
    const float* W1    = (const float*)d_in[2];
    const float* b1    = (const float*)d_in[3];
    const float* W2    = (const float*)d_in[4];
    const float* b2    = (const float*)d_in[5];
    const float* Wg    = (const float*)d_in[6];
    const float* bg    = (const float*)d_in[7];
    const float* a_src = (const float*)d_in[8];
    const float* a_dst = (const float*)d_in[9];
    const float* Wcls  = (const float*)d_in[10];
    const float* bcls  = (const float*)d_in[11];
    const float* Wl    = (const float*)d_in[12];
    const float* bl    = (const float*)d_in[13];

    const int N = in_sizes[0] / DIM;
    const int E = in_sizes[1] / 2;
    const int* src = eidx;
    const int* dst = eidx + E;

    // workspace layout (4B elems):
    // deg | rowstart | cursor | csr_src | csr_eid | bufA | bufB | e_s | e_d | sexp
    int*   deg      = (int*)d_ws;
    int*   rowstart = deg + N;
    int*   cursor   = rowstart + (N + 1);
    int*   csr_src  = cursor + N;
    int*   csr_eid  = csr_src + E;
    float* bufA     = (float*)(csr_eid + E);           // x1, later h
    float* bufB     = bufA + (size_t)N * DIM;          // x2
    float* e_s      = bufB + (size_t)N * DIM;
    float* e_d      = e_s + (size_t)N * HEADS;
    float* sexp     = e_d + (size_t)N * HEADS;         // E*HEADS

    float* out_cls  = (float*)d_out;                   // [N, 64]
    float* out_link = out_cls + (size_t)N * NCLS;      // [N, 1]

    int blkE  = (E + 255) / 256;
    int blkEH = (E * HEADS + 255) / 256;

    // ---- CSR build (once; shared by all three aggregation passes)
    hipMemsetAsync(deg, 0, (size_t)N * sizeof(int), stream);
    deg_hist<<<blkE, 256, 0, stream>>>(dst, deg, E);
    scan_kernel<<<1, SCAN_THREADS, 0, stream>>>(deg, rowstart, N);
    hipMemsetAsync(cursor, 0, (size_t)N * sizeof(int), stream);
    fill_csr<<<blkE, 256, 0, stream>>>(src, dst, rowstart, cursor, csr_src, csr_eid, E);

    // ---- GCN layers (gather, no atomics)
    gcn_fused<<<N, DIM, 0, stream>>>(xin,  rowstart, csr_src, W1, b1, bufA);  // x1
    gcn_fused<<<N, DIM, 0, stream>>>(bufA, rowstart, csr_src, W2, b2, bufB);  // x2

    // ---- classifier head
    classifier_kernel<<<N, NCLS, 0, stream>>>(bufB, Wcls, bcls, out_cls);

    // ---- GAT branch (bufA reusable after layer 2 consumed it)
    gat_h_kernel<<<N, DIM, 0, stream>>>(xin, Wg, a_src, a_dst, bufA, e_s, e_d);
    gat_score<<<blkEH, 256, 0, stream>>>(src, dst, e_s, e_d, sexp, E);
    gat_fused<<<N, DIM, 0, stream>>>(bufA, rowstart, csr_src, csr_eid, sexp,
                                     bg, Wl, bl, out_link);
}

// Round 3
// 631.835 us; speedup vs baseline: 2.5316x; 1.3302x over previous
//
#include <hip/hip_runtime.h>
#include <math.h>

#define DIM      128
#define HEADS    8
#define NCLS     64
#define NEG_SLOPE 0.2f
#define SCAN_THREADS 1024
#define NPB      64    // nodes per block in GEMM-tiled kernels
#define APAD     132   // LDS row stride (floats): keeps rows 16B-aligned, banks offset by 4/row

// ----------------------------------------------------------- degree histogram
__global__ void deg_hist(const int* __restrict__ dst, int* __restrict__ deg, int E) {
    int e = blockIdx.x * blockDim.x + threadIdx.x;
    if (e < E) atomicAdd(&deg[dst[e]], 1);
}

// ------------------- single-block exclusive scan over N degrees -> rowstart
__global__ void scan_kernel(const int* __restrict__ deg, int* __restrict__ rowstart, int N) {
    __shared__ int sums[SCAN_THREADS];
    int t = threadIdx.x;
    int chunk = (N + SCAN_THREADS - 1) / SCAN_THREADS;
    int beg = t * chunk;
    int end = min(beg + chunk, N);
    int s = 0;
    for (int i = beg; i < end; ++i) s += deg[i];
    sums[t] = s;
    __syncthreads();
    for (int off = 1; off < SCAN_THREADS; off <<= 1) {
        int v = (t >= off) ? sums[t - off] : 0;
        __syncthreads();
        sums[t] += v;
        __syncthreads();
    }
    int run = (t == 0) ? 0 : sums[t - 1];
    for (int i = beg; i < end; ++i) { rowstart[i] = run; run += deg[i]; }
    if (t == SCAN_THREADS - 1) rowstart[N] = sums[SCAN_THREADS - 1];
}

// -------------------------------------------- bucket fill: 1 atomic per edge
__global__ void fill_csr(const int* __restrict__ src, const int* __restrict__ dst,
                         const int* __restrict__ rowstart, int* __restrict__ cursor,
                         int* __restrict__ csr_src, int* __restrict__ csr_eid, int E) {
    int e = blockIdx.x * blockDim.x + threadIdx.x;
    if (e >= E) return;
    int d = dst[e];
    int pos = rowstart[d] + atomicAdd(&cursor[d], 1);
    csr_src[pos] = src[e];
    csr_eid[pos] = e;
}

// ===== GCN layer: 64-node tile. Phase 1: wave-per-node unrolled gather -> LDS.
//       Phase 2: register-blocked GEMM (4 nodes x 8 feats / thread), W via L1/L2
//       once per block (64x fewer W reads than per-node matvec).
__global__ __launch_bounds__(256, 4)
void gcn_fused2(const float* __restrict__ x, const int* __restrict__ rowstart,
                const int* __restrict__ csr_src, const float* __restrict__ W,
                const float* __restrict__ b, float* __restrict__ out, int N) {
    __shared__ float A[NPB * APAD];
    int n0 = blockIdx.x * NPB;
    int tid = threadIdx.x;
    int wave = tid >> 6, lane = tid & 63;
    const float2* xf = (const float2*)x;

    // Phase 1: each wave gathers 16 nodes; lane covers 2 feats; edge loop x4 unrolled
    for (int i = 0; i < 16; ++i) {
        int nl = wave * 16 + i;
        int n = n0 + nl;
        float2 acc = make_float2(0.f, 0.f);
        if (n < N) {
            int beg = rowstart[n], end = rowstart[n + 1];
            int it = beg;
            for (; it + 4 <= end; it += 4) {
                int s0 = csr_src[it], s1 = csr_src[it + 1];
                int s2 = csr_src[it + 2], s3 = csr_src[it + 3];
                float2 v0 = xf[(size_t)s0 * 64 + lane];
                float2 v1 = xf[(size_t)s1 * 64 + lane];
                float2 v2 = xf[(size_t)s2 * 64 + lane];
                float2 v3 = xf[(size_t)s3 * 64 + lane];
                acc.x += (v0.x + v1.x) + (v2.x + v3.x);
                acc.y += (v0.y + v1.y) + (v2.y + v3.y);
            }
            for (; it < end; ++it) {
                float2 v = xf[(size_t)csr_src[it] * 64 + lane];
                acc.x += v.x; acc.y += v.y;
            }
            float inv = 1.f / fmaxf((float)(end - beg), 1.f);
            acc.x *= inv; acc.y *= inv;
        }
        A[nl * APAD + 2 * lane]     = acc.x;
        A[nl * APAD + 2 * lane + 1] = acc.y;
    }
    __syncthreads();

    // Phase 2: GEMM. thread -> feats [f0,f0+8), nodes [nm,nm+4)
    int fg = tid & 15, ng = tid >> 4;
    int f0 = fg * 8, nm = ng * 4;
    float acc[4][8];
#pragma unroll
    for (int r = 0; r < 4; ++r)
#pragma unroll
        for (int c = 0; c < 8; ++c) acc[r][c] = 0.f;

    const float4* W4 = (const float4*)W;
#pragma unroll 4
    for (int k = 0; k < DIM; ++k) {
        float av[4];
#pragma unroll
        for (int r = 0; r < 4; ++r) av[r] = A[(nm + r) * APAD + k];
        float wv[8];
        *(float4*)&wv[0] = W4[k * 32 + fg * 2];
        *(float4*)&wv[4] = W4[k * 32 + fg * 2 + 1];
#pragma unroll
        for (int r = 0; r < 4; ++r)
#pragma unroll
            for (int c = 0; c < 8; ++c) acc[r][c] = fmaf(av[r], wv[c], acc[r][c]);
    }
    float bias[8];
    *(float4*)&bias[0] = ((const float4*)b)[fg * 2];
    *(float4*)&bias[4] = ((const float4*)b)[fg * 2 + 1];
#pragma unroll
    for (int r = 0; r < 4; ++r) {
        int n = n0 + nm + r;
        if (n < N) {
            float4 o0, o1;
            o0.x = fmaxf(acc[r][0] + bias[0], 0.f); o0.y = fmaxf(acc[r][1] + bias[1], 0.f);
            o0.z = fmaxf(acc[r][2] + bias[2], 0.f); o0.w = fmaxf(acc[r][3] + bias[3], 0.f);
            o1.x = fmaxf(acc[r][4] + bias[4], 0.f); o1.y = fmaxf(acc[r][5] + bias[5], 0.f);
            o1.z = fmaxf(acc[r][6] + bias[6], 0.f); o1.w = fmaxf(acc[r][7] + bias[7], 0.f);
            float4* op = (float4*)(out + (size_t)n * DIM + f0);
            op[0] = o0; op[1] = o1;
        }
    }
}

// ===== GAT h: 64-node tile GEMM h = x @ Wg, with e_s/e_d dot epilogue
__global__ __launch_bounds__(256, 4)
void gat_h2(const float* __restrict__ x, const float* __restrict__ Wg,
            const float* __restrict__ a_src, const float* __restrict__ a_dst,
            float* __restrict__ h, float* __restrict__ e_s, float* __restrict__ e_d, int N) {
    __shared__ float A[NPB * APAD];
    int n0 = blockIdx.x * NPB;
    int tid = threadIdx.x;
    // tile load: 64 nodes x 32 float4
    for (int idx = tid; idx < NPB * 32; idx += 256) {
        int nl = idx >> 5, q = idx & 31;
        int n = n0 + nl;
        float4 v = (n < N) ? ((const float4*)x)[(size_t)n * 32 + q]
                           : make_float4(0.f, 0.f, 0.f, 0.f);
        *(float4*)&A[nl * APAD + q * 4] = v;
    }
    __syncthreads();

    int fg = tid & 15, ng = tid >> 4;
    int f0 = fg * 8, nm = ng * 4;
    float acc[4][8];
#pragma unroll
    for (int r = 0; r < 4; ++r)
#pragma unroll
        for (int c = 0; c < 8; ++c) acc[r][c] = 0.f;

    const float4* W4 = (const float4*)Wg;
#pragma unroll 4
    for (int k = 0; k < DIM; ++k) {
        float av[4];
#pragma unroll
        for (int r = 0; r < 4; ++r) av[r] = A[(nm + r) * APAD + k];
        float wv[8];
        *(float4*)&wv[0] = W4[k * 32 + fg * 2];
        *(float4*)&wv[4] = W4[k * 32 + fg * 2 + 1];
#pragma unroll
        for (int r = 0; r < 4; ++r)
#pragma unroll
            for (int c = 0; c < 8; ++c) acc[r][c] = fmaf(av[r], wv[c], acc[r][c]);
    }
    // epilogue: store h rows; per-(node,head) attention dots (2 threads/head, shfl pair-sum)
    int head = fg >> 1, sub = (fg & 1) * 8;
    float as[8], ad[8];
#pragma unroll
    for (int j = 0; j < 8; ++j) {
        as[j] = a_src[head * 16 + sub + j];
        ad[j] = a_dst[head * 16 + sub + j];
    }
#pragma unroll
    for (int r = 0; r < 4; ++r) {
        int n = n0 + nm + r;
        float ps = 0.f, pd = 0.f;
#pragma unroll
        for (int c = 0; c < 8; ++c) {
            ps = fmaf(acc[r][c], as[c], ps);
            pd = fmaf(acc[r][c], ad[c], pd);
        }
        ps += __shfl_xor(ps, 1);
        pd += __shfl_xor(pd, 1);
        if (n < N) {
            float4 o0 = {acc[r][0], acc[r][1], acc[r][2], acc[r][3]};
            float4 o1 = {acc[r][4], acc[r][5], acc[r][6], acc[r][7]};
            float4* hp = (float4*)(h + (size_t)n * DIM + f0);
            hp[0] = o0; hp[1] = o1;
            if (!(fg & 1)) {
                e_s[n * HEADS + head] = ps;
                e_d[n * HEADS + head] = pd;
            }
        }
    }
}

// ---------------- per edge-head: sexp = exp(leaky_relu(e_s[src]+e_d[dst]))
__global__ void gat_score(const int* __restrict__ src, const int* __restrict__ dst,
                          const float* __restrict__ e_s, const float* __restrict__ e_d,
                          float* __restrict__ sexp, int E) {
    int tid = blockIdx.x * blockDim.x + threadIdx.x;
    if (tid >= E * HEADS) return;
    int e = tid >> 3;
    int hh = tid & (HEADS - 1);
    float sc = e_s[src[e] * HEADS + hh] + e_d[dst[e] * HEADS + hh];
    sc = (sc > 0.0f) ? sc : NEG_SLOPE * sc;
    sexp[tid] = expf(sc);           // max-shift skipped: |sc| small, fp32-safe
}

// ===== GAT aggregate + link head: wave-per-node, float2 lanes, x4 unroll
__global__ __launch_bounds__(256, 8)
void gat_fused2(const float* __restrict__ h, const int* __restrict__ rowstart,
                const int* __restrict__ csr_src, const int* __restrict__ csr_eid,
                const float* __restrict__ sexp, const float* __restrict__ bg,
                const float* __restrict__ Wl, const float* __restrict__ bl,
                float* __restrict__ out_link, int N) {
    int wave = threadIdx.x >> 6, lane = threadIdx.x & 63;
    int n = blockIdx.x * 4 + wave;
    if (n >= N) return;
    int head = lane >> 3;           // 2 feats per lane -> head = (2*lane)/16
    const float2* hf = (const float2*)h;
    int beg = rowstart[n], end = rowstart[n + 1];
    float2 acc = make_float2(0.f, 0.f);
    float den = 0.f;
    int it = beg;
    for (; it + 4 <= end; it += 4) {
        int s0 = csr_src[it], s1 = csr_src[it + 1], s2 = csr_src[it + 2], s3 = csr_src[it + 3];
        int e0 = csr_eid[it], e1 = csr_eid[it + 1], e2 = csr_eid[it + 2], e3 = csr_eid[it + 3];
        float ex0 = sexp[(size_t)e0 * HEADS + head];
        float ex1 = sexp[(size_t)e1 * HEADS + head];
        float ex2 = sexp[(size_t)e2 * HEADS + head];
        float ex3 = sexp[(size_t)e3 * HEADS + head];
        float2 v0 = hf[(size_t)s0 * 64 + lane];
        float2 v1 = hf[(size_t)s1 * 64 + lane];
        float2 v2 = hf[(size_t)s2 * 64 + lane];
        float2 v3 = hf[(size_t)s3 * 64 + lane];
        den += (ex0 + ex1) + (ex2 + ex3);
        acc.x = fmaf(v0.x, ex0, acc.x); acc.y = fmaf(v0.y, ex0, acc.y);
        acc.x = fmaf(v1.x, ex1, acc.x); acc.y = fmaf(v1.y, ex1, acc.y);
        acc.x = fmaf(v2.x, ex2, acc.x); acc.y = fmaf(v2.y, ex2, acc.y);
        acc.x = fmaf(v3.x, ex3, acc.x); acc.y = fmaf(v3.y, ex3, acc.y);
    }
    for (; it < end; ++it) {
        int s = csr_src[it], e = csr_eid[it];
        float ex = sexp[(size_t)e * HEADS + head];
        float2 v = hf[(size_t)s * 64 + lane];
        den += ex;
        acc.x = fmaf(v.x, ex, acc.x); acc.y = fmaf(v.y, ex, acc.y);
    }
    float inv = 1.f / (den + 1e-9f);
    float2 bgv = ((const float2*)bg)[lane];
    float x0 = fmaxf(acc.x * inv + bgv.x, 0.f);
    float x1 = fmaxf(acc.y * inv + bgv.y, 0.f);
    float2 wl = ((const float2*)Wl)[lane];
    float p = fmaf(x0, wl.x, x1 * wl.y);
    for (int off = 32; off; off >>= 1) p += __shfl_xor(p, off);
    if (lane == 0) out_link[n] = 1.f / (1.f + expf(-(p + bl[0])));
}

// ===== classifier: 64-node x 64-class tiled GEMM + in-register softmax
__global__ __launch_bounds__(256, 4)
void classifier2(const float* __restrict__ x2, const float* __restrict__ Wcls,
                 const float* __restrict__ bcls, float* __restrict__ out, int N) {
    __shared__ float A[NPB * APAD];
    int n0 = blockIdx.x * NPB;
    int tid = threadIdx.x;
    for (int idx = tid; idx < NPB * 32; idx += 256) {
        int nl = idx >> 5, q = idx & 31;
        int n = n0 + nl;
        float4 v = (n < N) ? ((const float4*)x2)[(size_t)n * 32 + q]
                           : make_float4(0.f, 0.f, 0.f, 0.f);
        *(float4*)&A[nl * APAD + q * 4] = v;
    }
    __syncthreads();

    int cg = tid & 15, ng = tid >> 4;     // 4 classes, 4 nodes per thread
    int c0 = cg * 4, nm = ng * 4;
    float acc[4][4];
#pragma unroll
    for (int r = 0; r < 4; ++r)
#pragma unroll
        for (int c = 0; c < 4; ++c) acc[r][c] = 0.f;

    const float4* W4 = (const float4*)Wcls;   // [128][16 float4]
#pragma unroll 4
    for (int k = 0; k < DIM; ++k) {
        float av[4];
#pragma unroll
        for (int r = 0; r < 4; ++r) av[r] = A[(nm + r) * APAD + k];
        float wv[4];
        *(float4*)&wv[0] = W4[k * 16 + cg];
#pragma unroll
        for (int r = 0; r < 4; ++r)
#pragma unroll
            for (int c = 0; c < 4; ++c) acc[r][c] = fmaf(av[r], wv[c], acc[r][c]);
    }
    float4 bv = ((const float4*)bcls)[cg];
    float bias[4] = {bv.x, bv.y, bv.z, bv.w};
#pragma unroll
    for (int r = 0; r < 4; ++r) {
        int n = n0 + nm + r;
        float l[4];
        float m = -1e30f;
#pragma unroll
        for (int c = 0; c < 4; ++c) { l[c] = acc[r][c] + bias[c]; m = fmaxf(m, l[c]); }
        for (int off = 1; off < 16; off <<= 1) m = fmaxf(m, __shfl_xor(m, off));
        float s = 0.f;
#pragma unroll
        for (int c = 0; c < 4; ++c) { l[c] = expf(l[c] - m); s += l[c]; }
        for (int off = 1; off < 16; off <<= 1) s += __shfl_xor(s, off);
        float invs = 1.f / s;
        if (n < N) {
            float4 o = {l[0] * invs, l[1] * invs, l[2] * invs, l[3] * invs};
            *(float4*)(out + (size_t)n * NCLS + c0) = o;
        }
    }
}

extern "C" void kernel_launch(void* const* d_in, const int* in_sizes, int n_in,
                              void* d_out, int out_size, void* d_ws, size_t ws_size,
                              hipStream_t stream) {
    const float* xin   = (const float*)d_in[0];
    const int*   eidx  = (const int*)  d_in[1];
    const float* W1    = (const float*)d_in[2];
    const float* b1    = (const float*)d_in[3];
    const float* W2    = (const float*)d_in[4];
    const float* b2    = (const float*)d_in[5];
    const float* Wg    = (const float*)d_in[6];
    const float* bg    = (const float*)d_in[7];
    const float* a_src = (const float*)d_in[8];
    const float* a_dst = (const float*)d_in[9];
    const float* Wcls  = (const float*)d_in[10];
    const float* bcls  = (const float*)d_in[11];
    const float* Wl    = (const float*)d_in[12];
    const float* bl    = (const float*)d_in[13];

    const int N = in_sizes[0] / DIM;
    const int E = in_sizes[1] / 2;
    const int* src = eidx;
    const int* dst = eidx + E;

    // workspace layout (4B elems):
    int*   deg      = (int*)d_ws;
    int*   rowstart = deg + N;
    int*   cursor   = rowstart + (N + 1);
    int*   csr_src  = cursor + N;
    int*   csr_eid  = csr_src + E;
    float* bufA     = (float*)(csr_eid + E);           // x1, later h
    float* bufB     = bufA + (size_t)N * DIM;          // x2
    float* e_s      = bufB + (size_t)N * DIM;
    float* e_d      = e_s + (size_t)N * HEADS;
    float* sexp     = e_d + (size_t)N * HEADS;         // E*HEADS

    float* out_cls  = (float*)d_out;                   // [N, 64]
    float* out_link = out_cls + (size_t)N * NCLS;      // [N, 1]

    int blkE  = (E + 255) / 256;
    int blkEH = (E * HEADS + 255) / 256;
    int blkN64 = (N + NPB - 1) / NPB;

    // ---- CSR build (once; shared by all three aggregation passes)
    hipMemsetAsync(deg, 0, (size_t)N * sizeof(int), stream);
    deg_hist<<<blkE, 256, 0, stream>>>(dst, deg, E);
    scan_kernel<<<1, SCAN_THREADS, 0, stream>>>(deg, rowstart, N);
    hipMemsetAsync(cursor, 0, (size_t)N * sizeof(int), stream);
    fill_csr<<<blkE, 256, 0, stream>>>(src, dst, rowstart, cursor, csr_src, csr_eid, E);

    // ---- GCN layers (gather + tiled GEMM, no atomics)
    gcn_fused2<<<blkN64, 256, 0, stream>>>(xin,  rowstart, csr_src, W1, b1, bufA, N);
    gcn_fused2<<<blkN64, 256, 0, stream>>>(bufA, rowstart, csr_src, W2, b2, bufB, N);

    // ---- classifier head
    classifier2<<<blkN64, 256, 0, stream>>>(bufB, Wcls, bcls, out_cls, N);

    // ---- GAT branch (bufA reusable after GCN2 consumed it)
    gat_h2<<<blkN64, 256, 0, stream>>>(xin, Wg, a_src, a_dst, bufA, e_s, e_d, N);
    gat_score<<<blkEH, 256, 0, stream>>>(src, dst, e_s, e_d, sexp, E);
    gat_fused2<<<(N + 3) / 4, 256, 0, stream>>>(bufA, rowstart, csr_src, csr_eid, sexp,
                                                bg, Wl, bl, out_link, N);
}